// Round 4
// baseline (182.203 us; speedup 1.0000x reference)
//
#include <hip/hip_runtime.h>

#define T_LEN 128
#define NB_BINS 15

// ---------------------------------------------------------------------------
// k0: per-sequence static dots gs/bs -> d_ws
// ---------------------------------------------------------------------------
__global__ __launch_bounds__(256) void k_static(
    const float4* __restrict__ C4,
    const float4* __restrict__ wgs4,
    const float4* __restrict__ wbs4,
    float* __restrict__ gs_out, float* __restrict__ bs_out, int n_seq)
{
    int n = blockIdx.x * blockDim.x + threadIdx.x;
    if (n >= n_seq) return;
    float gs = 0.0f, bs = 0.0f;
    #pragma unroll
    for (int i = 0; i < 4; ++i) {
        float4 c = C4[n * 4 + i];
        float4 wg = wgs4[i];
        float4 wb = wbs4[i];
        gs += c.x * wg.x + c.y * wg.y + c.z * wg.z + c.w * wg.w;
        bs += c.x * wb.x + c.y * wb.y + c.z * wb.z + c.w * wb.w;
    }
    gs_out[n] = gs;
    bs_out[n] = bs;
}

// ---------------------------------------------------------------------------
// k1: streaming pass over L (R1's proven-good pattern: 8 lanes/row, waves read
// 1KiB contiguous per instruction, grid-stride rows). Emits per-step scalars
//   a[row] = gA*S + gd + gs          (zpm additive term)
//   c[row] = b0 + bin + bd + bs + bT*t/30   (logit additive term)
// staged in-place into d_out's Zf (a) and Zv (c) regions.
// ---------------------------------------------------------------------------
__global__ __launch_bounds__(256) void k_pre(
    const float4* __restrict__ L4,
    const float*  __restrict__ S,
    const float*  __restrict__ gs_in,
    const float*  __restrict__ bs_in,
    const float4* __restrict__ wgd4,
    const float4* __restrict__ wbd4,
    const float*  __restrict__ p_gA,
    const float*  __restrict__ p_b0,
    const float*  __restrict__ p_bbins,
    const float*  __restrict__ p_bT,
    float* __restrict__ a_out,
    float* __restrict__ c_out,
    int total_rows)
{
    __shared__ float sbins[NB_BINS];
    if (threadIdx.x < NB_BINS) sbins[threadIdx.x] = p_bbins[threadIdx.x];
    __syncthreads();

    const float gA   = p_gA[0];
    const float b0   = p_b0[0];
    const float bT30 = p_bT[0] * (1.0f / 30.0f);

    const int tid   = blockIdx.x * blockDim.x + threadIdx.x;
    const int lane8 = tid & 7;
    const float4 wg = wgd4[lane8];
    const float4 wb = wbd4[lane8];

    const int group   = tid >> 3;
    const int ngroups = (gridDim.x * blockDim.x) >> 3;

    // explicit one-iteration prefetch of the L vector
    int row = group;
    float4 v = (row < total_rows) ? L4[(size_t)row * 8 + lane8]
                                  : make_float4(0, 0, 0, 0);
    for (; row < total_rows; row += ngroups) {
        const int nrow = row + ngroups;
        float4 vn = v;
        if (nrow < total_rows) vn = L4[(size_t)nrow * 8 + lane8];

        float g = v.x * wg.x + v.y * wg.y + v.z * wg.z + v.w * wg.w;
        float b = v.x * wb.x + v.y * wb.y + v.z * wb.z + v.w * wb.w;
        #pragma unroll
        for (int off = 1; off < 8; off <<= 1) {
            g += __shfl_xor(g, off, 64);
            b += __shfl_xor(b, off, 64);
        }

        // all 8 lanes compute a,c (same values; no divergence)
        const int n = row >> 7;
        const int t = row & 127;
        const float s_v = S[row];
        const float gsv = gs_in[n];
        const float bsv = bs_in[n];
        int cnt = (int)fmaxf(0.0f, fminf(14.0f,
                      ceilf(fmaf(s_v, 3.0f, 7.5f)) - 1.0f));
        const float a = gA * s_v + g + gsv;
        const float c = b0 + sbins[cnt] + b + bsv + bT30 * (float)t;

        if (lane8 == 0) { a_out[row] = a; c_out[row] = c; }
        v = vn;
    }
}

// ---------------------------------------------------------------------------
// k2: per-sequence scan. 4 lanes/seq redundant (16 seqs/wave, 2048 waves).
// Quad structure: 16 timesteps per quad; per-chunk broadcast f4 loads
// (prefetched one quad ahead), per-lane stashed f4 results -> dense stores.
// Reads a,c in place from Zf/Zv regions and overwrites with Z mean/var.
// ---------------------------------------------------------------------------
__global__ __launch_bounds__(256) void k_scan(
    const float4* Ain,     // aliases Zf region (a staged)
    const float4* Cin,     // aliases Zv region (c staged)
    const float4* __restrict__ Y4,
    const float4* __restrict__ M4,
    const float*  __restrict__ p_psi,
    const float*  __restrict__ p_lsz,
    const float*  __restrict__ p_bZ,
    float4* Zf4,           // aliases Ain
    float4* Zv4,           // aliases Cin
    float* __restrict__ ll_out)
{
    const int gtid = blockIdx.x * blockDim.x + threadIdx.x;
    const int n = gtid >> 2;
    const int s = gtid & 3;

    const float psi  = p_psi[0];
    const float e    = __expf(p_lsz[0]);
    const float sig2 = e * e;
    const float bZ   = p_bZ[0];
    const float psi2 = psi * psi;
    const float bZ2  = bZ * bZ;

    const int b32 = n * 32;    // float4 index base (128 steps / 4)

    float zm = 0.0f, zvv = 1.0f, ll = 0.0f;

#define STEP(AA, CC, YY, MM, PMOUT, PVOUT, PROUT) do {                    \
        const float zpm = fmaf(psi, zm, (AA));                            \
        const float zpv = fmaf(psi2, zvv, sig2);                          \
        float logit = fmaf(bZ, zpm, (CC));                                \
        logit = fminf(fmaxf(logit, -20.0f), 20.0f);                       \
        const float prob = __builtin_amdgcn_rcpf(1.0f + __expf(-logit));  \
        const float grad = ((YY) - prob) * bZ * (MM);                     \
        const float hess = fmaf(bZ2 * prob * (1.0f - prob), (MM), 1e-6f); \
        const float pvv  = __builtin_amdgcn_rcpf(                         \
                             __builtin_amdgcn_rcpf(zpv + 1e-8f) + hess);  \
        const float pmm  = fmaf(pvv, grad, zpm);                          \
        zm = pmm; zvv = pvv;                                              \
        PMOUT = pmm; PVOUT = pvv; PROUT = prob;                           \
    } while (0)

#define CHUNK(J, Aq, Cq, Yq, Mq) do {                                     \
        float pm0, pm1, pm2, pm3, pv0, pv1, pv2, pv3, pr0, pr1, pr2, pr3; \
        STEP(Aq.x, Cq.x, Yq.x, Mq.x, pm0, pv0, pr0);                      \
        STEP(Aq.y, Cq.y, Yq.y, Mq.y, pm1, pv1, pr1);                      \
        STEP(Aq.z, Cq.z, Yq.z, Mq.z, pm2, pv2, pr2);                      \
        STEP(Aq.w, Cq.w, Yq.w, Mq.w, pm3, pv3, pr3);                      \
        const float prs = (s == 0) ? pr0 : (s == 1) ? pr1                 \
                        : (s == 2) ? pr2 : pr3;                           \
        const float ys  = (s == 0) ? Yq.x : (s == 1) ? Yq.y               \
                        : (s == 2) ? Yq.z : Yq.w;                         \
        const float ms  = (s == 0) ? Mq.x : (s == 1) ? Mq.y               \
                        : (s == 2) ? Mq.z : Mq.w;                         \
        ll += (ys * __logf(prs + 1e-10f)                                  \
             + (1.0f - ys) * __logf(1.0f - prs + 1e-10f)) * ms;           \
        if (s == (J)) {                                                   \
            stpm = make_float4(pm0, pm1, pm2, pm3);                       \
            stpv = make_float4(pv0, pv1, pv2, pv3);                       \
        }                                                                 \
    } while (0)

    // preload quad 0 (16 steps; broadcast loads, all 4 lanes same addr)
    float4 A0 = Ain[b32 + 0], A1 = Ain[b32 + 1], A2 = Ain[b32 + 2], A3 = Ain[b32 + 3];
    float4 C0 = Cin[b32 + 0], C1 = Cin[b32 + 1], C2 = Cin[b32 + 2], C3 = Cin[b32 + 3];
    float4 Y0 = Y4[b32 + 0],  Y1 = Y4[b32 + 1],  Y2 = Y4[b32 + 2],  Y3 = Y4[b32 + 3];
    float4 M0 = M4[b32 + 0],  M1 = M4[b32 + 1],  M2 = M4[b32 + 2],  M3 = M4[b32 + 3];

    for (int Q = 0; Q < 8; ++Q) {
        // prefetch quad Q+1
        float4 An0, An1, An2, An3, Cn0, Cn1, Cn2, Cn3;
        float4 Yn0, Yn1, Yn2, Yn3, Mn0, Mn1, Mn2, Mn3;
        if (Q < 7) {
            const int qb = b32 + 4 * (Q + 1);
            An0 = Ain[qb + 0]; An1 = Ain[qb + 1]; An2 = Ain[qb + 2]; An3 = Ain[qb + 3];
            Cn0 = Cin[qb + 0]; Cn1 = Cin[qb + 1]; Cn2 = Cin[qb + 2]; Cn3 = Cin[qb + 3];
            Yn0 = Y4[qb + 0];  Yn1 = Y4[qb + 1];  Yn2 = Y4[qb + 2];  Yn3 = Y4[qb + 3];
            Mn0 = M4[qb + 0];  Mn1 = M4[qb + 1];  Mn2 = M4[qb + 2];  Mn3 = M4[qb + 3];
        }

        float4 stpm = make_float4(0, 0, 0, 0);
        float4 stpv = make_float4(0, 0, 0, 0);
        CHUNK(0, A0, C0, Y0, M0);
        CHUNK(1, A1, C1, Y1, M1);
        CHUNK(2, A2, C2, Y2, M2);
        CHUNK(3, A3, C3, Y3, M3);

        // dense stores: lane s writes its stashed chunk (64B per group)
        Zf4[b32 + 4 * Q + s] = stpm;
        Zv4[b32 + 4 * Q + s] = stpv;

        if (Q < 7) {
            A0 = An0; A1 = An1; A2 = An2; A3 = An3;
            C0 = Cn0; C1 = Cn1; C2 = Cn2; C3 = Cn3;
            Y0 = Yn0; Y1 = Yn1; Y2 = Yn2; Y3 = Yn3;
            M0 = Mn0; M1 = Mn1; M2 = Mn2; M3 = Mn3;
        }
    }
#undef CHUNK
#undef STEP

    // every lane owns distinct (chunk, element) ll terms -> full-wave sum
    #pragma unroll
    for (int off = 1; off < 64; off <<= 1) ll += __shfl_xor(ll, off, 64);
    if ((threadIdx.x & 63) == 0) atomicAdd(ll_out, ll);
}

// ---------------------------------------------------------------------------
extern "C" void kernel_launch(void* const* d_in, const int* in_sizes, int n_in,
                              void* d_out, int out_size, void* d_ws, size_t ws_size,
                              hipStream_t stream) {
    const float* S     = (const float*)d_in[0];
    const float* L     = (const float*)d_in[1];
    const float* C     = (const float*)d_in[2];
    const float* Y     = (const float*)d_in[3];
    const float* M     = (const float*)d_in[4];
    const float* psi   = (const float*)d_in[5];
    const float* gA    = (const float*)d_in[6];
    const float* wgd   = (const float*)d_in[7];
    const float* wgs   = (const float*)d_in[8];
    const float* lsz   = (const float*)d_in[9];
    const float* b0    = (const float*)d_in[10];
    const float* bZ    = (const float*)d_in[11];
    const float* bbins = (const float*)d_in[12];
    const float* wbd   = (const float*)d_in[13];
    const float* wbs   = (const float*)d_in[14];
    const float* bT    = (const float*)d_in[15];

    const int NT    = in_sizes[0];        // N*T = 4194304
    const int n_seq = NT / T_LEN;         // 32768

    float* zf = (float*)d_out;            // Zf region; staging for a
    float* zv = zf + NT;                  // Zv region; staging for c
    float* ll = zf + 2 * (size_t)NT;      // scalar ll

    float* gs_ws = (float*)d_ws;          // [n_seq]
    float* bs_ws = gs_ws + n_seq;         // [n_seq]

    hipMemsetAsync((void*)ll, 0, sizeof(float), stream);

    // k0: static dots
    k_static<<<(n_seq + 255) / 256, 256, 0, stream>>>(
        reinterpret_cast<const float4*>(C),
        reinterpret_cast<const float4*>(wgs),
        reinterpret_cast<const float4*>(wbs),
        gs_ws, bs_ws, n_seq);

    // k1: streaming precompute of a,c (into zf/zv)
    k_pre<<<2048, 256, 0, stream>>>(
        reinterpret_cast<const float4*>(L),
        S, gs_ws, bs_ws,
        reinterpret_cast<const float4*>(wgd),
        reinterpret_cast<const float4*>(wbd),
        gA, b0, bbins, bT,
        zf, zv, NT);

    // k2: scan (in-place over zf/zv)
    k_scan<<<(n_seq * 4) / 256, 256, 0, stream>>>(
        reinterpret_cast<const float4*>(zf),
        reinterpret_cast<const float4*>(zv),
        reinterpret_cast<const float4*>(Y),
        reinterpret_cast<const float4*>(M),
        psi, lsz, bZ,
        reinterpret_cast<float4*>(zf),
        reinterpret_cast<float4*>(zv),
        ll);
}